// Round 4
// baseline (177.744 us; speedup 1.0000x reference)
//
#include <hip/hip_runtime.h>
#include <hip/hip_bf16.h>
#include <math.h>

#define HIDDEN 1024
#define EMB    256
#define BROWS  4096
#define CAND   128
#define LN_EPS 1e-12f

#define NENT   (BROWS * CAND)     // 524288 entries
#define NB     1024               // vocab buckets
#define BKT_SH 9                  // bucket = idx >> 9  (max 976 < 1024)

typedef unsigned int u32;
typedef __attribute__((ext_vector_type(8))) short bf16x8;
typedef __attribute__((ext_vector_type(4))) float f32x4;

__device__ __forceinline__ int swz(int row, int slot) { return slot ^ ((row >> 1) & 3); }

__device__ __forceinline__ unsigned short f2bf(float f) {
    __bf16 h = (__bf16)f;
    return __builtin_bit_cast(unsigned short, h);
}
__device__ __forceinline__ float bf2f(unsigned short u) {
    return __builtin_bit_cast(float, (u32)u << 16);
}

// ---------------------------------------------------------------------------
// Fused: Hbf = bf16( LayerNorm(GELU(A @ W^T + b)) * gamma + beta )
// BM=16, BN=256(full row -> LN fused), BK=32; grid=256 (1 block/CU).
// ---------------------------------------------------------------------------
__global__ __launch_bounds__(256) void k_transform(
    const float* __restrict__ A,
    const float* __restrict__ W,
    const float* __restrict__ bias,
    const float* __restrict__ gamma,
    const float* __restrict__ beta,
    unsigned short* __restrict__ Hbf)
{
    __shared__ unsigned short As[16 * 32];
    __shared__ unsigned short Ws[256 * 32];
    __shared__ float part[16][8];

    const int tid  = threadIdx.x;
    const int lane = tid & 63;
    const int wv   = tid >> 6;
    const int m0   = blockIdx.x * 16;

    const int lcol = lane & 15;
    const int lk   = lane >> 4;

    f32x4 acc[4] = {};

    for (int kt = 0; kt < HIDDEN; kt += 32) {
        float4 a0, a1;
        const int arow = tid >> 2, apr = tid & 3;
        if (tid < 64) {
            a0 = *(const float4*)&A[(size_t)(m0 + arow) * HIDDEN + kt + apr * 8];
            a1 = *(const float4*)&A[(size_t)(m0 + arow) * HIDDEN + kt + apr * 8 + 4];
        }
        float4 w0[4], w1[4];
        #pragma unroll
        for (int i = 0; i < 4; ++i) {
            int id = tid + i * 256;
            int row = id >> 2, pr = id & 3;
            w0[i] = *(const float4*)&W[(size_t)row * HIDDEN + kt + pr * 8];
            w1[i] = *(const float4*)&W[(size_t)row * HIDDEN + kt + pr * 8 + 4];
        }
        __syncthreads();
        if (tid < 64) {
            bf16x8 v;
            v[0]=f2bf(a0.x); v[1]=f2bf(a0.y); v[2]=f2bf(a0.z); v[3]=f2bf(a0.w);
            v[4]=f2bf(a1.x); v[5]=f2bf(a1.y); v[6]=f2bf(a1.z); v[7]=f2bf(a1.w);
            *(bf16x8*)&As[arow * 32 + swz(arow, apr) * 8] = v;
        }
        #pragma unroll
        for (int i = 0; i < 4; ++i) {
            int id = tid + i * 256;
            int row = id >> 2, pr = id & 3;
            bf16x8 v;
            v[0]=f2bf(w0[i].x); v[1]=f2bf(w0[i].y); v[2]=f2bf(w0[i].z); v[3]=f2bf(w0[i].w);
            v[4]=f2bf(w1[i].x); v[5]=f2bf(w1[i].y); v[6]=f2bf(w1[i].z); v[7]=f2bf(w1[i].w);
            *(bf16x8*)&Ws[row * 32 + swz(row, pr) * 8] = v;
        }
        __syncthreads();
        bf16x8 af = *(const bf16x8*)&As[lcol * 32 + swz(lcol, lk) * 8];
        bf16x8 bfr[4];
        #pragma unroll
        for (int n = 0; n < 4; ++n) {
            int r = wv * 64 + n * 16 + lcol;
            bfr[n] = *(const bf16x8*)&Ws[r * 32 + swz(r, lk) * 8];
        }
        #pragma unroll
        for (int n = 0; n < 4; ++n)
            acc[n] = __builtin_amdgcn_mfma_f32_16x16x32_bf16(af, bfr[n], acc[n], 0, 0, 0);
    }

    float bcol[4], gcol[4], becol[4];
    #pragma unroll
    for (int n = 0; n < 4; ++n) {
        int col = wv * 64 + n * 16 + lcol;
        bcol[n]  = bias[col];
        gcol[n]  = gamma[col];
        becol[n] = beta[col];
    }

    float sv[4] = {}, qv[4] = {};
    #pragma unroll
    for (int n = 0; n < 4; ++n) {
        #pragma unroll
        for (int r = 0; r < 4; ++r) {
            float v = acc[n][r] + bcol[n];
            v = 0.5f * v * (1.0f + erff(v * 0.70710678118654752f));
            acc[n][r] = v;
            sv[r] += v;
            qv[r] += v * v;
        }
    }
    #pragma unroll
    for (int r = 0; r < 4; ++r) {
        #pragma unroll
        for (int msk = 8; msk >= 1; msk >>= 1) {
            sv[r] += __shfl_xor(sv[r], msk);
            qv[r] += __shfl_xor(qv[r], msk);
        }
    }
    if (lcol == 0) {
        #pragma unroll
        for (int r = 0; r < 4; ++r) {
            int R = lk * 4 + r;
            part[R][wv * 2 + 0] = sv[r];
            part[R][wv * 2 + 1] = qv[r];
        }
    }
    __syncthreads();

    #pragma unroll
    for (int r = 0; r < 4; ++r) {
        int R = lk * 4 + r;
        float4 p0 = *(const float4*)&part[R][0];
        float4 p1 = *(const float4*)&part[R][4];
        float s  = p0.x + p0.z + p1.x + p1.z;
        float q  = p0.y + p0.w + p1.y + p1.w;
        float mu = s * (1.0f / 256.0f);
        float var = q * (1.0f / 256.0f) - mu * mu;
        float rs = rsqrtf(var + LN_EPS);
        #pragma unroll
        for (int n = 0; n < 4; ++n) {
            int col = wv * 64 + n * 16 + lcol;
            Hbf[(size_t)(m0 + R) * EMB + col] = f2bf((acc[n][r] - mu) * rs * gcol[n] + becol[n]);
        }
    }
}

// ---------------------------------------------------------------------------
// Bucketing passes. Cursors padded to 64B stride to avoid L2 line contention.
// ---------------------------------------------------------------------------
__global__ __launch_bounds__(256) void k_zero(u32* __restrict__ bkt_pad)
{
    bkt_pad[blockIdx.x * 256 + threadIdx.x] = 0;   // grid 64 -> 16384 slots
}

__global__ __launch_bounds__(256) void k_count(
    const int* __restrict__ cidx, u32* __restrict__ bkt_pad)
{
    __shared__ u32 lh[NB];
    const int tid = threadIdx.x;
    for (int t = tid; t < NB; t += 256) lh[t] = 0;
    __syncthreads();
    const int base = blockIdx.x * 8192;
    #pragma unroll
    for (int i = 0; i < 32; ++i) {
        int idx = cidx[base + i * 256 + tid];
        atomicAdd(&lh[idx >> BKT_SH], 1u);
    }
    __syncthreads();
    for (int t = tid; t < NB; t += 256) {
        u32 v = lh[t];
        if (v) atomicAdd(&bkt_pad[t * 16], v);
    }
}

__global__ __launch_bounds__(1024) void k_scan(u32* __restrict__ bkt_pad)
{
    __shared__ u32 a[NB];
    const int t = threadIdx.x;
    const u32 own = bkt_pad[t * 16];
    a[t] = own;
    __syncthreads();
    for (int off = 1; off < NB; off <<= 1) {
        u32 add = (t >= off) ? a[t - off] : 0u;
        __syncthreads();
        a[t] += add;
        __syncthreads();
    }
    bkt_pad[t * 16] = a[t] - own;   // exclusive prefix -> cursor
}

__global__ __launch_bounds__(256) void k_scatter(
    const int* __restrict__ cidx, u32* __restrict__ bkt_pad,
    u32* __restrict__ ent_idx, u32* __restrict__ ent_e)
{
    __shared__ u32 lh[NB];
    __shared__ u32 lb[NB];
    __shared__ u32 lo[NB];
    const int tid = threadIdx.x;
    for (int t = tid; t < NB; t += 256) { lh[t] = 0; lo[t] = 0; }
    __syncthreads();
    const int base = blockIdx.x * 8192;
    u32 iv[32];
    #pragma unroll
    for (int i = 0; i < 32; ++i) {
        iv[i] = (u32)cidx[base + i * 256 + tid];
        atomicAdd(&lh[iv[i] >> BKT_SH], 1u);
    }
    __syncthreads();
    for (int t = tid; t < NB; t += 256) {
        u32 v = lh[t];
        if (v) lb[t] = atomicAdd(&bkt_pad[t * 16], v);
    }
    __syncthreads();
    #pragma unroll
    for (int i = 0; i < 32; ++i) {
        u32 bkt = iv[i] >> BKT_SH;
        u32 p = lb[bkt] + atomicAdd(&lo[bkt], 1u);
        ent_idx[p] = iv[i];
        ent_e[p]   = (u32)(base + i * 256 + tid);
    }
}

// ---------------------------------------------------------------------------
// Gather in bucket order. XCD-chunked block swizzle: each XCD walks a
// contiguous ~61MB table range; duplicate rows are bucket-adjacent -> L2 hits.
// 16 lanes per entry, 4 entries per wave per iter, 8 iters per wave.
// ---------------------------------------------------------------------------
__global__ __launch_bounds__(256) void k_gather(
    const unsigned short* __restrict__ Hbf,
    const float* __restrict__ table,
    const float* __restrict__ ebias,
    const u32* __restrict__ ent_idx,
    const u32* __restrict__ ent_e,
    float* __restrict__ out)
{
    const int bid  = blockIdx.x;
    const int work = (bid & 7) * 512 + (bid >> 3);   // 4096 = 8 XCDs x 512
    const int tid  = threadIdx.x;
    const int lane = tid & 63;
    const int wv   = tid >> 6;
    const int l    = lane & 15;
    const int q    = lane >> 4;

    const int ebase = work * 128 + wv * 32 + q;
    u32 idxs[8], es[8];
    #pragma unroll
    for (int it = 0; it < 8; ++it) {
        idxs[it] = ent_idx[ebase + it * 4];
        es[it]   = ent_e[ebase + it * 4];
    }

    #pragma unroll
    for (int it = 0; it < 8; ++it) {
        const float4* row = (const float4*)(table + (size_t)idxs[it] * EMB);
        const u32 e = es[it];
        const unsigned short* hrow = Hbf + (size_t)(e >> 7) * EMB;

        float4 t0 = row[ 0 + l];
        float4 t1 = row[16 + l];
        float4 t2 = row[32 + l];
        float4 t3 = row[48 + l];
        ushort4 h0 = *(const ushort4*)&hrow[  0 + l * 4];
        ushort4 h1 = *(const ushort4*)&hrow[ 64 + l * 4];
        ushort4 h2 = *(const ushort4*)&hrow[128 + l * 4];
        ushort4 h3 = *(const ushort4*)&hrow[192 + l * 4];

        float s = t0.x*bf2f(h0.x) + t0.y*bf2f(h0.y) + t0.z*bf2f(h0.z) + t0.w*bf2f(h0.w)
                + t1.x*bf2f(h1.x) + t1.y*bf2f(h1.y) + t1.z*bf2f(h1.z) + t1.w*bf2f(h1.w)
                + t2.x*bf2f(h2.x) + t2.y*bf2f(h2.y) + t2.z*bf2f(h2.z) + t2.w*bf2f(h2.w)
                + t3.x*bf2f(h3.x) + t3.y*bf2f(h3.y) + t3.z*bf2f(h3.z) + t3.w*bf2f(h3.w);
        #pragma unroll
        for (int m = 8; m >= 1; m >>= 1) s += __shfl_xor(s, m);
        if (l == 0) out[e] = s + ebias[idxs[it]];
    }
}

// ---------------------------------------------------------------------------
extern "C" void kernel_launch(void* const* d_in, const int* in_sizes, int n_in,
                              void* d_out, int out_size, void* d_ws, size_t ws_size,
                              hipStream_t stream) {
    const float* hidden = (const float*)d_in[0];
    const float* Wd     = (const float*)d_in[1];
    const float* bd     = (const float*)d_in[2];
    const float* gamma  = (const float*)d_in[3];
    const float* beta   = (const float*)d_in[4];
    const float* table  = (const float*)d_in[5];
    const float* ebias  = (const float*)d_in[6];
    const int*   cidx   = (const int*)d_in[7];
    float* out = (float*)d_out;

    char* ws = (char*)d_ws;
    unsigned short* Hbf  = (unsigned short*)(ws);                 // 2 MB
    u32* bkt_pad         = (u32*)(ws + 2097152);                  // 64 KB (1024 x 16 u32)
    u32* ent_idx         = (u32*)(ws + 2097152 + 65536);          // 2 MB
    u32* ent_e           = (u32*)(ws + 2097152 + 65536 + 2097152);// 2 MB

    k_transform<<<dim3(BROWS / 16), 256, 0, stream>>>(hidden, Wd, bd, gamma, beta, Hbf);
    k_zero<<<dim3(64), 256, 0, stream>>>(bkt_pad);
    k_count<<<dim3(64), 256, 0, stream>>>(cidx, bkt_pad);
    k_scan<<<dim3(1), 1024, 0, stream>>>(bkt_pad);
    k_scatter<<<dim3(64), 256, 0, stream>>>(cidx, bkt_pad, ent_idx, ent_e);
    k_gather<<<dim3(NENT / 128), 256, 0, stream>>>(Hbf, table, ebias, ent_idx, ent_e, out);
}

// Round 5
// 135.220 us; speedup vs baseline: 1.3145x; 1.3145x over previous
//
#include <hip/hip_runtime.h>
#include <hip/hip_bf16.h>
#include <math.h>

#define HIDDEN 1024
#define EMB    256
#define BROWS  4096
#define CAND   128
#define LN_EPS 1e-12f

typedef __attribute__((ext_vector_type(8))) short bf16x8;
typedef __attribute__((ext_vector_type(4))) float f32x4;

__device__ __forceinline__ int swz(int row, int slot) { return slot ^ ((row >> 1) & 3); }

__device__ __forceinline__ unsigned short f2bf(float f) {
    __bf16 h = (__bf16)f;
    return __builtin_bit_cast(unsigned short, h);
}

// ---------------------------------------------------------------------------
// Fused: G = LayerNorm(GELU(A @ W^T + b)) * gamma + beta   (f32 out)
// BM=16, BN=256(full row -> LN fused), BK=32; grid=256 (1 block/CU).
// 4 waves, each 16Mx64N (1x4 frags of 16x16x32 bf16 MFMA, fp32 accum).
// ---------------------------------------------------------------------------
__global__ __launch_bounds__(256) void k_transform(
    const float* __restrict__ A,
    const float* __restrict__ W,
    const float* __restrict__ bias,
    const float* __restrict__ gamma,
    const float* __restrict__ beta,
    float* __restrict__ G)
{
    __shared__ unsigned short As[16 * 32];
    __shared__ unsigned short Ws[256 * 32];
    __shared__ float part[16][8];

    const int tid  = threadIdx.x;
    const int lane = tid & 63;
    const int wv   = tid >> 6;
    const int m0   = blockIdx.x * 16;

    const int lcol = lane & 15;
    const int lk   = lane >> 4;

    f32x4 acc[4] = {};

    for (int kt = 0; kt < HIDDEN; kt += 32) {
        float4 a0, a1;
        const int arow = tid >> 2, apr = tid & 3;
        if (tid < 64) {
            a0 = *(const float4*)&A[(size_t)(m0 + arow) * HIDDEN + kt + apr * 8];
            a1 = *(const float4*)&A[(size_t)(m0 + arow) * HIDDEN + kt + apr * 8 + 4];
        }
        float4 w0[4], w1[4];
        #pragma unroll
        for (int i = 0; i < 4; ++i) {
            int id = tid + i * 256;
            int row = id >> 2, pr = id & 3;
            w0[i] = *(const float4*)&W[(size_t)row * HIDDEN + kt + pr * 8];
            w1[i] = *(const float4*)&W[(size_t)row * HIDDEN + kt + pr * 8 + 4];
        }
        __syncthreads();
        if (tid < 64) {
            bf16x8 v;
            v[0]=f2bf(a0.x); v[1]=f2bf(a0.y); v[2]=f2bf(a0.z); v[3]=f2bf(a0.w);
            v[4]=f2bf(a1.x); v[5]=f2bf(a1.y); v[6]=f2bf(a1.z); v[7]=f2bf(a1.w);
            *(bf16x8*)&As[arow * 32 + swz(arow, apr) * 8] = v;
        }
        #pragma unroll
        for (int i = 0; i < 4; ++i) {
            int id = tid + i * 256;
            int row = id >> 2, pr = id & 3;
            bf16x8 v;
            v[0]=f2bf(w0[i].x); v[1]=f2bf(w0[i].y); v[2]=f2bf(w0[i].z); v[3]=f2bf(w0[i].w);
            v[4]=f2bf(w1[i].x); v[5]=f2bf(w1[i].y); v[6]=f2bf(w1[i].z); v[7]=f2bf(w1[i].w);
            *(bf16x8*)&Ws[row * 32 + swz(row, pr) * 8] = v;
        }
        __syncthreads();
        bf16x8 af = *(const bf16x8*)&As[lcol * 32 + swz(lcol, lk) * 8];
        bf16x8 bfr[4];
        #pragma unroll
        for (int n = 0; n < 4; ++n) {
            int r = wv * 64 + n * 16 + lcol;
            bfr[n] = *(const bf16x8*)&Ws[r * 32 + swz(r, lk) * 8];
        }
        #pragma unroll
        for (int n = 0; n < 4; ++n)
            acc[n] = __builtin_amdgcn_mfma_f32_16x16x32_bf16(af, bfr[n], acc[n], 0, 0, 0);
    }

    float bcol[4], gcol[4], becol[4];
    #pragma unroll
    for (int n = 0; n < 4; ++n) {
        int col = wv * 64 + n * 16 + lcol;
        bcol[n]  = bias[col];
        gcol[n]  = gamma[col];
        becol[n] = beta[col];
    }

    float sv[4] = {}, qv[4] = {};
    #pragma unroll
    for (int n = 0; n < 4; ++n) {
        #pragma unroll
        for (int r = 0; r < 4; ++r) {
            float v = acc[n][r] + bcol[n];
            v = 0.5f * v * (1.0f + erff(v * 0.70710678118654752f));
            acc[n][r] = v;
            sv[r] += v;
            qv[r] += v * v;
        }
    }
    #pragma unroll
    for (int r = 0; r < 4; ++r) {
        #pragma unroll
        for (int msk = 8; msk >= 1; msk >>= 1) {
            sv[r] += __shfl_xor(sv[r], msk);
            qv[r] += __shfl_xor(qv[r], msk);
        }
    }
    if (lcol == 0) {
        #pragma unroll
        for (int r = 0; r < 4; ++r) {
            int R = lk * 4 + r;
            part[R][wv * 2 + 0] = sv[r];
            part[R][wv * 2 + 1] = qv[r];
        }
    }
    __syncthreads();

    #pragma unroll
    for (int r = 0; r < 4; ++r) {
        int R = lk * 4 + r;
        float4 p0 = *(const float4*)&part[R][0];
        float4 p1 = *(const float4*)&part[R][4];
        float s  = p0.x + p0.z + p1.x + p1.z;
        float q  = p0.y + p0.w + p1.y + p1.w;
        float mu = s * (1.0f / 256.0f);
        float var = q * (1.0f / 256.0f) - mu * mu;
        float rs = rsqrtf(var + LN_EPS);
        #pragma unroll
        for (int n = 0; n < 4; ++n) {
            int col = wv * 64 + n * 16 + lcol;
            G[(size_t)(m0 + R) * EMB + col] = (acc[n][r] - mu) * rs * gcol[n] + becol[n];
        }
    }
}

// ---------------------------------------------------------------------------
// scores[b,c] = dot(table[idx[b,c]], H[b]) + ebias[idx[b,c]]
// Block = 64 candidates of one b (2 blocks/b). Each wave owns 16 candidates
// and a private 16KB LDS segment. 16 x 1KB row DMAs issued back-to-back via
// global_load_lds (no VGPR data cost, ~16KB in flight per wave), consumed in
// groups of 4 behind counted vmcnt waits (never drained early). 64KB LDS ->
// 2 blocks/CU -> ~128KB in flight per CU >> Little's-law requirement.
// ---------------------------------------------------------------------------
__global__ __launch_bounds__(256) void k_scores(
    const float* __restrict__ H,
    const float* __restrict__ table,
    const float* __restrict__ ebias,
    const int*   __restrict__ cidx,
    float* __restrict__ out)
{
    __shared__ float smem[16384];   // 64 KB: 4 waves x 16 rows x 256 f32
    const int tid  = threadIdx.x;
    const int lane = tid & 63;
    const int wv   = tid >> 6;
    const int l    = lane & 15;   // lane within candidate group
    const int q    = lane >> 4;   // candidate group 0..3
    const int b     = blockIdx.x >> 1;
    const int cbase = (blockIdx.x & 1) * 64 + wv * 16;

    // prefetch H fragment, candidate indices, entity biases (before DMAs)
    const float4* Hrow = (const float4*)(H + (size_t)b * EMB);
    float4 hv[4];
    #pragma unroll
    for (int p = 0; p < 4; ++p) hv[p] = Hrow[p * 16 + l];

    const int sidxv = cidx[(size_t)b * CAND + cbase + l];   // lane j -> cand (j&15)
    const float ebv = ebias[sidxv];

    // issue 16 row DMAs into this wave's LDS segment
    float* wbase = &smem[wv * 4096];
    #pragma unroll
    for (int r = 0; r < 16; ++r) {
        int idx = __shfl(sidxv, r);
        const float* gsrc = table + (size_t)idx * EMB + lane * 4;  // lane*16B
        __builtin_amdgcn_global_load_lds(
            (const __attribute__((address_space(1))) void*)gsrc,
            (__attribute__((address_space(3))) void*)(wbase + r * 256),
            16, 0, 0);
    }

    float res[4];
    // counted waits: vmcnt retires oldest-first, so rows 0..4(g+1)-1 are
    // guaranteed complete regardless of other VM ops interleaved by compiler.
#define DOGROUP(g, WN)                                                        \
    {                                                                         \
        asm volatile("s_waitcnt vmcnt(" WN ")" ::: "memory");                 \
        const float4* row = (const float4*)(wbase + (4 * (g) + q) * 256);     \
        float s = 0.f;                                                        \
        _Pragma("unroll")                                                     \
        for (int p = 0; p < 4; ++p) {                                         \
            float4 t = row[p * 16 + l];                                       \
            s += t.x * hv[p].x + t.y * hv[p].y + t.z * hv[p].z + t.w * hv[p].w;\
        }                                                                     \
        _Pragma("unroll")                                                     \
        for (int m = 8; m >= 1; m >>= 1) s += __shfl_xor(s, m);               \
        res[g] = s;                                                           \
    }
    DOGROUP(0, "12")
    DOGROUP(1, "8")
    DOGROUP(2, "4")
    DOGROUP(3, "0")
#undef DOGROUP

    #pragma unroll
    for (int g = 0; g < 4; ++g) {
        float eb = __shfl(ebv, 4 * g + q);
        if (l == 0) out[(size_t)b * CAND + cbase + 4 * g + q] = res[g] + eb;
    }
}

// ---------------------------------------------------------------------------
extern "C" void kernel_launch(void* const* d_in, const int* in_sizes, int n_in,
                              void* d_out, int out_size, void* d_ws, size_t ws_size,
                              hipStream_t stream) {
    const float* hidden = (const float*)d_in[0];
    const float* Wd     = (const float*)d_in[1];
    const float* bd     = (const float*)d_in[2];
    const float* gamma  = (const float*)d_in[3];
    const float* beta   = (const float*)d_in[4];
    const float* table  = (const float*)d_in[5];
    const float* ebias  = (const float*)d_in[6];
    const int*   cidx   = (const int*)d_in[7];
    float* out = (float*)d_out;

    float* G = (float*)d_ws;   // 4096*256 f32 = 4 MB

    k_transform<<<dim3(BROWS / 16), 256, 0, stream>>>(hidden, Wd, bd, gamma, beta, G);
    k_scores<<<dim3(BROWS * 2), 256, 0, stream>>>(G, table, ebias, cidx, out);
}

// Round 6
// 119.636 us; speedup vs baseline: 1.4857x; 1.1303x over previous
//
#include <hip/hip_runtime.h>
#include <hip/hip_bf16.h>
#include <math.h>

#define HIDDEN 1024
#define EMB    256
#define BROWS  4096
#define CAND   128
#define LN_EPS 1e-12f

typedef __attribute__((ext_vector_type(8))) short bf16x8;
typedef __attribute__((ext_vector_type(4))) float f32x4;

__device__ __forceinline__ int swz(int row, int slot) { return slot ^ ((row >> 1) & 3); }

__device__ __forceinline__ unsigned short f2bf(float f) {
    __bf16 h = (__bf16)f;
    return __builtin_bit_cast(unsigned short, h);
}

__device__ __forceinline__ float gelu(float x) {
    return 0.5f * x * (1.0f + erff(x * 0.70710678118654752f));
}

// ---------------------------------------------------------------------------
// Split-K GEMM: P[s] = A[:, s*256:(s+1)*256] @ W[:, s*256:(s+1)*256]^T
// grid (256 m-tiles, 4 k-slices) = 1024 blocks -> 4 blocks/CU so the
// barrier-pipeline latencies overlap 4-way; register prefetch of the next
// K-tile is issued before the MFMA phase. BM=16, BK=32, 8 iters/block.
// ---------------------------------------------------------------------------
__global__ __launch_bounds__(256) void k_gemm_partial(
    const float* __restrict__ A,
    const float* __restrict__ W,
    float* __restrict__ P)               // [4][4096][256]
{
    __shared__ unsigned short As[16 * 32];
    __shared__ unsigned short Ws[256 * 32];

    const int tid  = threadIdx.x;
    const int lane = tid & 63;
    const int wv   = tid >> 6;
    const int m0   = blockIdx.x * 16;
    const int ks   = blockIdx.y;
    const int kbeg = ks * 256;

    const int lcol = lane & 15;
    const int lk   = lane >> 4;
    const int arow = tid >> 2, apr = tid & 3;

    float4 a0, a1, w0[4], w1[4];

#define LOADREGS(KT)                                                          \
    if (tid < 64) {                                                           \
        a0 = *(const float4*)&A[(size_t)(m0 + arow) * HIDDEN + (KT) + apr * 8];     \
        a1 = *(const float4*)&A[(size_t)(m0 + arow) * HIDDEN + (KT) + apr * 8 + 4]; \
    }                                                                         \
    _Pragma("unroll")                                                         \
    for (int i = 0; i < 4; ++i) {                                             \
        int id = tid + i * 256;                                               \
        int row = id >> 2, pr = id & 3;                                       \
        w0[i] = *(const float4*)&W[(size_t)row * HIDDEN + (KT) + pr * 8];     \
        w1[i] = *(const float4*)&W[(size_t)row * HIDDEN + (KT) + pr * 8 + 4]; \
    }

    f32x4 acc[4] = {};
    LOADREGS(kbeg)

    for (int it = 0; it < 8; ++it) {
        __syncthreads();                  // prev iter's frag reads complete
        if (tid < 64) {
            bf16x8 v;
            v[0]=f2bf(a0.x); v[1]=f2bf(a0.y); v[2]=f2bf(a0.z); v[3]=f2bf(a0.w);
            v[4]=f2bf(a1.x); v[5]=f2bf(a1.y); v[6]=f2bf(a1.z); v[7]=f2bf(a1.w);
            *(bf16x8*)&As[arow * 32 + swz(arow, apr) * 8] = v;
        }
        #pragma unroll
        for (int i = 0; i < 4; ++i) {
            int id = tid + i * 256;
            int row = id >> 2, pr = id & 3;
            bf16x8 v;
            v[0]=f2bf(w0[i].x); v[1]=f2bf(w0[i].y); v[2]=f2bf(w0[i].z); v[3]=f2bf(w0[i].w);
            v[4]=f2bf(w1[i].x); v[5]=f2bf(w1[i].y); v[6]=f2bf(w1[i].z); v[7]=f2bf(w1[i].w);
            *(bf16x8*)&Ws[row * 32 + swz(row, pr) * 8] = v;
        }
        __syncthreads();
        if (it < 7) { LOADREGS(kbeg + (it + 1) * 32) }   // prefetch next tile
        bf16x8 af = *(const bf16x8*)&As[lcol * 32 + swz(lcol, lk) * 8];
        bf16x8 bfr[4];
        #pragma unroll
        for (int n = 0; n < 4; ++n) {
            int r = wv * 64 + n * 16 + lcol;
            bfr[n] = *(const bf16x8*)&Ws[r * 32 + swz(r, lk) * 8];
        }
        #pragma unroll
        for (int n = 0; n < 4; ++n)
            acc[n] = __builtin_amdgcn_mfma_f32_16x16x32_bf16(af, bfr[n], acc[n], 0, 0, 0);
    }
#undef LOADREGS

    float* Pout = P + (size_t)ks * ((size_t)BROWS * EMB);
    #pragma unroll
    for (int n = 0; n < 4; ++n)
        #pragma unroll
        for (int r = 0; r < 4; ++r) {
            int R   = lk * 4 + r;
            int col = wv * 64 + n * 16 + lcol;
            Pout[(size_t)(m0 + R) * EMB + col] = acc[n][r];
        }
}

// ---------------------------------------------------------------------------
// Finalize: G = LN(GELU(sum_s P[s] + bias)) * gamma + beta. One wave per row.
// ---------------------------------------------------------------------------
__global__ __launch_bounds__(256) void k_finalize(
    const float* __restrict__ P,
    const float* __restrict__ bias,
    const float* __restrict__ gamma,
    const float* __restrict__ beta,
    float* __restrict__ G)
{
    const int tid  = threadIdx.x;
    const int lane = tid & 63;
    const int row  = blockIdx.x * 4 + (tid >> 6);
    const size_t off = (size_t)row * EMB + lane * 4;
    const size_t S   = (size_t)BROWS * EMB;

    float4 v0 = *(const float4*)&P[off];
    float4 v1 = *(const float4*)&P[off + S];
    float4 v2 = *(const float4*)&P[off + 2 * S];
    float4 v3 = *(const float4*)&P[off + 3 * S];
    float4 bb = *(const float4*)&bias[lane * 4];

    float4 h;
    h.x = gelu(v0.x + v1.x + v2.x + v3.x + bb.x);
    h.y = gelu(v0.y + v1.y + v2.y + v3.y + bb.y);
    h.z = gelu(v0.z + v1.z + v2.z + v3.z + bb.z);
    h.w = gelu(v0.w + v1.w + v2.w + v3.w + bb.w);

    float s = h.x + h.y + h.z + h.w;
    #pragma unroll
    for (int m = 32; m >= 1; m >>= 1) s += __shfl_xor(s, m);
    const float mu = s * (1.0f / 256.0f);

    const float dx = h.x - mu, dy = h.y - mu, dz = h.z - mu, dw = h.w - mu;
    float q = dx * dx + dy * dy + dz * dz + dw * dw;
    #pragma unroll
    for (int m = 32; m >= 1; m >>= 1) q += __shfl_xor(q, m);
    const float rs = rsqrtf(q * (1.0f / 256.0f) + LN_EPS);

    float4 g  = *(const float4*)&gamma[lane * 4];
    float4 be = *(const float4*)&beta[lane * 4];
    float4 o;
    o.x = dx * rs * g.x + be.x;
    o.y = dy * rs * g.y + be.y;
    o.z = dz * rs * g.z + be.z;
    o.w = dw * rs * g.w + be.w;
    *(float4*)&G[off] = o;
}

// ---------------------------------------------------------------------------
// scores[b,c] = dot(table[idx[b,c]], H[b]) + ebias[idx[b,c]]
// (unchanged from round 5: LDS-DMA gather, counted vmcnt waits)
// ---------------------------------------------------------------------------
__global__ __launch_bounds__(256) void k_scores(
    const float* __restrict__ H,
    const float* __restrict__ table,
    const float* __restrict__ ebias,
    const int*   __restrict__ cidx,
    float* __restrict__ out)
{
    __shared__ float smem[16384];   // 64 KB: 4 waves x 16 rows x 256 f32
    const int tid  = threadIdx.x;
    const int lane = tid & 63;
    const int wv   = tid >> 6;
    const int l    = lane & 15;
    const int q    = lane >> 4;
    const int b     = blockIdx.x >> 1;
    const int cbase = (blockIdx.x & 1) * 64 + wv * 16;

    const float4* Hrow = (const float4*)(H + (size_t)b * EMB);
    float4 hv[4];
    #pragma unroll
    for (int p = 0; p < 4; ++p) hv[p] = Hrow[p * 16 + l];

    const int sidxv = cidx[(size_t)b * CAND + cbase + l];
    const float ebv = ebias[sidxv];

    float* wbase = &smem[wv * 4096];
    #pragma unroll
    for (int r = 0; r < 16; ++r) {
        int idx = __shfl(sidxv, r);
        const float* gsrc = table + (size_t)idx * EMB + lane * 4;
        __builtin_amdgcn_global_load_lds(
            (const __attribute__((address_space(1))) void*)gsrc,
            (__attribute__((address_space(3))) void*)(wbase + r * 256),
            16, 0, 0);
    }

    float res[4];
#define DOGROUP(g, WN)                                                        \
    {                                                                         \
        asm volatile("s_waitcnt vmcnt(" WN ")" ::: "memory");                 \
        const float4* row = (const float4*)(wbase + (4 * (g) + q) * 256);     \
        float s = 0.f;                                                        \
        _Pragma("unroll")                                                     \
        for (int p = 0; p < 4; ++p) {                                         \
            float4 t = row[p * 16 + l];                                       \
            s += t.x * hv[p].x + t.y * hv[p].y + t.z * hv[p].z + t.w * hv[p].w;\
        }                                                                     \
        _Pragma("unroll")                                                     \
        for (int m = 8; m >= 1; m >>= 1) s += __shfl_xor(s, m);               \
        res[g] = s;                                                           \
    }
    DOGROUP(0, "12")
    DOGROUP(1, "8")
    DOGROUP(2, "4")
    DOGROUP(3, "0")
#undef DOGROUP

    #pragma unroll
    for (int g = 0; g < 4; ++g) {
        float eb = __shfl(ebv, 4 * g + q);
        if (l == 0) out[(size_t)b * CAND + cbase + 4 * g + q] = res[g] + eb;
    }
}

// ---------------------------------------------------------------------------
extern "C" void kernel_launch(void* const* d_in, const int* in_sizes, int n_in,
                              void* d_out, int out_size, void* d_ws, size_t ws_size,
                              hipStream_t stream) {
    const float* hidden = (const float*)d_in[0];
    const float* Wd     = (const float*)d_in[1];
    const float* bd     = (const float*)d_in[2];
    const float* gamma  = (const float*)d_in[3];
    const float* beta   = (const float*)d_in[4];
    const float* table  = (const float*)d_in[5];
    const float* ebias  = (const float*)d_in[6];
    const int*   cidx   = (const int*)d_in[7];
    float* out = (float*)d_out;

    char* ws = (char*)d_ws;
    float* G = (float*)ws;                          // 4 MB
    float* P = (float*)(ws + 4 * 1024 * 1024);      // 16 MB (4 x [4096,256] f32)

    k_gemm_partial<<<dim3(BROWS / 16, 4), 256, 0, stream>>>(hidden, Wd, P);
    k_finalize<<<dim3(BROWS / 4), 256, 0, stream>>>(P, bd, gamma, beta, G);
    k_scores<<<dim3(BROWS * 2), 256, 0, stream>>>(G, table, ebias, cidx, out);
}